// Round 5
// baseline (327.868 us; speedup 1.0000x reference)
//
#include <hip/hip_runtime.h>

typedef unsigned short ushort_t;
typedef unsigned char uchar_t;
typedef short short8 __attribute__((ext_vector_type(8)));
typedef unsigned short ushort8 __attribute__((ext_vector_type(8)));
typedef float floatx4 __attribute__((ext_vector_type(4)));
typedef unsigned int uint2v __attribute__((ext_vector_type(2)));
typedef unsigned int uint4v __attribute__((ext_vector_type(4)));

#define N_W 589824   // 256*256*3*3

static __device__ __forceinline__ unsigned short f2bf(float f) {
    unsigned int u = __float_as_uint(f);
    u = (u + 0x7FFFu + ((u >> 16) & 1u)) >> 16;   // round-to-nearest-even
    return (unsigned short)u;
}

// async 16B global -> LDS DMA; data lands at lds_base + lane*16 (wave-uniform base)
static __device__ __forceinline__ void g2l16(const void* g, void* lds_base_uniform) {
    __builtin_amdgcn_global_load_lds(
        (__attribute__((address_space(1))) void*)g,
        (__attribute__((address_space(3))) void*)lds_base_uniform,
        16, 0, 0);
}

// expand 8 ternary i8 codes {0x3F,0xBF,0x00} -> 8 bf16 {+1,-1,~0}
// bf16 = (code<<8)|0x80 via v_perm; zero becomes 0x0080 = 2^-126 (error <= 1e-36, negligible)
static __device__ __forceinline__ short8 expand_tern(uint2v c) {
    uint4v r;
    r[0] = __builtin_amdgcn_perm(0x80808080u, c[0], 0x01040004u);
    r[1] = __builtin_amdgcn_perm(0x80808080u, c[0], 0x03040204u);
    r[2] = __builtin_amdgcn_perm(0x80808080u, c[1], 0x01040004u);
    r[3] = __builtin_amdgcn_perm(0x80808080u, c[1], 0x03040204u);
    return __builtin_bit_cast(short8, r);
}

// sum 256 fp32 block partials in double (deterministic, order-insensitive at fp32 output)
static __device__ __forceinline__ float delta_from_parts(const float* __restrict__ part) {
    double s = 0.0;
    for (int k = 0; k < 256; ++k) s += (double)part[k];
    return 0.7f * (float)(s / (double)N_W);
}

// ---------------- kernel 1: per-block sum(|w|) -> part[256] (no memset, no atomic) ----------------
__global__ void absmean_kernel(const float* __restrict__ w, float* __restrict__ part) {
    int tid = blockIdx.x * blockDim.x + threadIdx.x;
    int stride = gridDim.x * blockDim.x;
    float local = 0.f;
    for (int i = tid; i < N_W; i += stride) local += fabsf(w[i]);
    for (int off = 32; off > 0; off >>= 1)
        local += __shfl_down(local, off, 64);
    __shared__ float pl[4];
    int lane = threadIdx.x & 63, wv = threadIdx.x >> 6;
    if (lane == 0) pl[wv] = local;
    __syncthreads();
    if (threadIdx.x == 0)
        part[blockIdx.x] = pl[0] + pl[1] + pl[2] + pl[3];
}

// -------- kernel 2 (fused prep): ternarize->i8 frags + border-zero + x NCHW->padded NHWC bf16 --------
// grid (51, 4, 32): x<49 interior xcvt; x==49 border; x==50 ternarize
// wtf i8 index: [cin_blk 8][r9 9][g(co64) 4][i 4][q 4][l 16][e 8]
__global__ __launch_bounds__(256)
void prep_kernel(const float* __restrict__ x, const float* __restrict__ w,
                 const float* __restrict__ part,
                 uchar_t* __restrict__ wtf, ushort_t* __restrict__ xp) {
    const int tid = threadIdx.x;

    if (blockIdx.x == 50) {           // ---- ternarize: 128 blocks x 4608 elems ----
        const int id = blockIdx.y * 32 + blockIdx.z;
        const float delta = delta_from_parts(part);
        for (int k = tid; k < 4608; k += 256) {
            int o = id * 4608 + k;
            int e   = o & 7;
            int l   = (o >> 3) & 15;
            int q   = (o >> 7) & 3;
            int i   = (o >> 9) & 3;
            int g   = (o >> 11) & 3;
            int t13 = o >> 13;               // 0..71
            int r9  = t13 % 9;
            int cb  = t13 / 9;
            int co  = g * 64 + i * 16 + l;
            int cin = cb * 32 + q * 8 + e;
            float v = w[(co * 256 + cin) * 9 + r9];
            wtf[o] = (v > delta) ? 0x3F : ((v < -delta) ? 0xBF : 0x00);
        }
        return;
    }

    if (blockIdx.x == 49) {           // ---- border zero: 128 blocks x 1824 chunks ----
        const int id = blockIdx.y * 32 + blockIdx.z;
        ushort8 z = (ushort8){0,0,0,0,0,0,0,0};
        for (int k = tid; k < 1824; k += 256) {
            int e = id * 1824 + k;           // 0..233471
            int cg   = e & 31;
            int rest = e >> 5;
            int pid  = rest % 228;
            int b    = rest / 228;
            int hh, ww;
            if (pid < 58)       { hh = 0;  ww = pid; }
            else if (pid < 116) { hh = 57; ww = pid - 58; }
            else {
                int p = pid - 116;
                hh = 1 + (p >> 1);
                ww = (p & 1) ? 57 : 0;
            }
            *(ushort8*)&xp[(((b * 58 + hh) * 58 + ww) << 8) + cg * 8] = z;
        }
        return;
    }

    // ---- interior xcvt ----
    __shared__ float tile[64][65];
    const int px0 = blockIdx.x * 64;
    const int ci0 = blockIdx.y * 64;
    const int b   = blockIdx.z;
    const int row  = tid >> 6;
    const int lane = tid & 63;
#pragma unroll
    for (int k = 0; k < 16; ++k) {
        int ci_l = row * 16 + k;
        tile[ci_l][lane] = x[(b * 256 + ci0 + ci_l) * 3136 + px0 + lane];
    }
    __syncthreads();
#pragma unroll
    for (int p = 0; p < 2; ++p) {
        int c    = tid + p * 256;   // 0..511
        int px_l = c >> 3;
        int cg   = c & 7;
        int px = px0 + px_l;
        int h = px / 56, w2 = px - h * 56;
        ushort8 v;
#pragma unroll
        for (int j = 0; j < 8; ++j) v[j] = f2bf(tile[cg * 8 + j][px_l]);
        *(ushort8*)&xp[(((b * 58 + h + 1) * 58 + (w2 + 1)) << 8) + ci0 + cg * 8] = v;
    }
}

// -------- kernel 2b (fallback path): old [r][co][cin] bf16 layout --------
__global__ void ternarize_kernel(const float* __restrict__ w, const float* __restrict__ part,
                                 ushort_t* __restrict__ wt) {
    int o = blockIdx.x * 256 + threadIdx.x;
    float delta = delta_from_parts(part);
    int cin = o & 255;
    int co  = (o >> 8) & 255;
    int r   = o >> 16;
    float v = w[(co * 256 + cin) * 9 + r];
    float t = (v > delta) ? 1.f : ((v < -delta) ? -1.f : 0.f);
    wt[o] = f2bf(t);
}

// ------------- kernel 4: shift-conv, bf16 MFMA, 4h x 8w px x 256 co blocks -------------
// grid: (98, 32) flat-swizzled over 8 XCDs (3136 % 8 == 0 -> bijective); block 256 = 4 waves.
// acc[4][2] = 32 AGPR + ~70 arch VGPR ~= 102 <= 128 -> 4 waves/SIMD (16 waves/CU).
// 3136 blocks / (256 CU x 4) = 3.06 rounds -> tail ~2% (vs 1568/768 = 2.04 rounds, ~20% tail).
// vmcnt(12) barrier: issue order per cb = [DMA x1][af x36]; vmcnt(12) retires the DMA while
// the 12 newest af prefetches (r9=6..8 rotations for next cb) stay in flight across s_barrier.
__global__ __launch_bounds__(256, 4)
void conv_mfma6_kernel(const ushort_t* __restrict__ xp, const uchar_t* __restrict__ wtf,
                       const float* __restrict__ alpha, const float* __restrict__ bias,
                       float* __restrict__ out) {
    // two halo buffers: [hr 6][wc 10][cig 4] = 240 slots of 16B, padded to 256
    __shared__ __align__(16) ushort_t lds_x[2 * 256 * 8];   // 8 KB

    const int tid  = threadIdx.x;
    // XCD-aware bijective swizzle of flat block id
    const int flat = blockIdx.y * 98 + blockIdx.x;
    const int swz  = (flat & 7) * 392 + (flat >> 3);
    const int b    = swz / 98;
    const int t98  = swz - b * 98;
    const int th   = t98 / 7;
    const int tw   = t98 - th * 7;
    const int h0   = th * 4;
    const int w0   = tw * 8;

    const int lane = tid & 63;
    const int wave = tid >> 6;
    const int l15  = lane & 15;
    const int quad = lane >> 4;
    const int hs   = l15 >> 3;      // px sub-row (0..1)
    const int ws   = l15 & 7;       // px sub-col (0..7)

    // ---- DMA slot descriptor (1 per thread; 240 real slots, 241..255 pad dup) ----
    const int ss  = (tid < 240) ? tid : 239;
    const int hr  = ss / 40;
    const int rem = ss - hr * 40;
    const int wc  = rem >> 2, cig = rem & 3;
    const unsigned goff = (unsigned)(((((b * 58 + h0 + hr) * 58) + (w0 + wc)) << 8) + (cig << 3)) * 2;
    const unsigned loff = (unsigned)((tid & ~63) * 16);     // wave-uniform base
    const char* xpb = (const char*)xp;

    floatx4 acc[4][2];
#pragma unroll
    for (int i = 0; i < 4; ++i)
#pragma unroll
        for (int j = 0; j < 2; ++j)
            acc[i][j] = (floatx4){0.f, 0.f, 0.f, 0.f};

    // A-fragment (i8) base: wtf[((cb*9 + r9)*4 + gsel)*2048 + i*512 + lane*8] (byte units)
    const int gsel = wave;                            // 4 waves = 4 co64 groups
    const uchar_t* wbase = wtf + gsel * 2048 + lane * 8;

    // prologue: halo DMA for cin_blk 0 into buf 0 — issued FIRST so it is oldest in vmcnt queue
    g2l16(xpb + goff, (char*)lds_x + loff);
    asm volatile("" ::: "memory");   // keep af loads issued after the DMA

    // af prologue for cb0 r=0..2 (compressed)
    uint2v afc[3][4];
#pragma unroll
    for (int r = 0; r < 3; ++r)
#pragma unroll
        for (int i = 0; i < 4; ++i)
            afc[r][i] = *(const uint2v*)(wbase + r * 8192 + i * 512);

    int cur = 0;
    for (int cb = 0; cb < 8; ++cb) {
        const uchar_t* wcb = wbase + cb * 73728;                     // 9*4*2048
        const uchar_t* wnx = wbase + ((cb < 7) ? cb + 1 : cb) * 73728;

        // counted-vmcnt barrier: retire DMA (oldest), keep 12 newest af prefetches in flight
        asm volatile("s_waitcnt vmcnt(12) lgkmcnt(0)" ::: "memory");
        __builtin_amdgcn_s_barrier();

        // issue next halo DMA into the other buffer (hidden behind this cb's compute)
        if (cb < 7)
            g2l16(xpb + goff + (cb + 1) * 64, (char*)lds_x + loff + (cur ^ 1) * 4096);
        asm volatile("" ::: "memory");   // af rotates must issue after the DMA

        const ushort_t* xb = lds_x + cur * 2048;

        // B-fragment double buffer (2 reads/r9)
        short8 bfv[2][2];
#pragma unroll
        for (int j = 0; j < 2; ++j)
            bfv[0][j] = *(const short8*)&xb[((hs + j * 2) * 10 + ws) * 32 + quad * 8];

#pragma unroll
        for (int r9 = 0; r9 < 9; ++r9) {
            if (r9 < 8) {
                const int kh1 = (r9 + 1) / 3;
                const int kw1 = (r9 + 1) - kh1 * 3;
#pragma unroll
                for (int j = 0; j < 2; ++j)
                    bfv[(r9 + 1) & 1][j] =
                        *(const short8*)&xb[((hs + j * 2 + kh1) * 10 + (ws + kw1)) * 32 + quad * 8];
            }
            // expand compressed A fragments (VALU, hides under MFMA pipe)
            short8 afx[4];
#pragma unroll
            for (int i = 0; i < 4; ++i)
                afx[i] = expand_tern(afc[r9 % 3][i]);

            __builtin_amdgcn_s_setprio(1);
#pragma unroll
            for (int i = 0; i < 4; ++i)
#pragma unroll
                for (int j = 0; j < 2; ++j)
                    acc[i][j] = __builtin_amdgcn_mfma_f32_16x16x32_bf16(
                        afx[i], bfv[r9 & 1][j], acc[i][j], 0, 0, 0);
            __builtin_amdgcn_s_setprio(0);

            // A rotate: r9<6 -> this cb's r9+3; r9>=6 -> NEXT cb's r9-6 (cross-cb prefetch)
            {
                const uchar_t* asrc = (r9 < 6) ? (wcb + (r9 + 3) * 8192)
                                               : (wnx + (r9 - 6) * 8192);
#pragma unroll
                for (int i = 0; i < 4; ++i)
                    afc[r9 % 3][i] = *(const uint2v*)(asrc + i * 512);
            }
        }
        cur ^= 1;
    }

    // ---- epilogue: D row = quad*4+r (co within 16), col = l15 -> px (hs,ws) ----
    const float a0 = alpha[0];
#pragma unroll
    for (int i = 0; i < 4; ++i) {
        int cob = gsel * 64 + i * 16 + quad * 4;
#pragma unroll
        for (int j = 0; j < 2; ++j) {
            int hh = h0 + j * 2 + hs;
            int ww = w0 + ws;
#pragma unroll
            for (int r = 0; r < 4; ++r) {
                int cog = cob + r;
                out[((b * 256 + cog) * 56 + hh) * 56 + ww] = acc[i][j][r] * a0 + bias[cog];
            }
        }
    }
}

// ------------- fallback conv (fp32-x staging, old wt layout) -------------
__global__ __launch_bounds__(256, 2)
void conv_mfma_fallback_kernel(const float* __restrict__ x, const ushort_t* __restrict__ wt,
                               const float* __restrict__ alpha, const float* __restrict__ bias,
                               float* __restrict__ out) {
    __shared__ __align__(16) ushort_t lds_x[10 * 18 * 40];
    __shared__ __align__(16) ushort_t lds_a[128 * 40];
    const int tid  = threadIdx.x;
    const int b    = blockIdx.y;
    const int th   = blockIdx.x >> 2;
    const int tw   = blockIdx.x & 3;
    const int h0   = th * 8;
    const int w0   = tw * 16;
    const int co0  = blockIdx.z * 128;
    const int lane = tid & 63;
    const int wave = tid >> 6;
    const int l15  = lane & 15;
    const int quad = lane >> 4;
    const int wco  = (wave & 1) * 64;
    const int wrow = (wave >> 1) * 4;
    floatx4 acc[4][4];
#pragma unroll
    for (int i = 0; i < 4; ++i)
#pragma unroll
        for (int j = 0; j < 4; ++j)
            acc[i][j] = (floatx4){0.f, 0.f, 0.f, 0.f};
    const int co_l = tid >> 1;
    const int half = tid & 1;
    for (int cin0 = 0; cin0 < 256; cin0 += 32) {
        for (int e = tid; e < 5760; e += 256) {
            int hc = e % 18;
            int t2 = e / 18;
            int hr = t2 % 10;
            int ci = t2 / 10;
            int hh = h0 - 1 + hr;
            int ww = w0 - 1 + hc;
            float v = 0.f;
            if (hh >= 0 && hh < 56 && ww >= 0 && ww < 56)
                v = x[((b * 256 + cin0 + ci) * 3136) + hh * 56 + ww];
            lds_x[(hr * 18 + hc) * 40 + ci] = f2bf(v);
        }
        for (int r9 = 0; r9 < 9; ++r9) {
            {
                const short8* src = (const short8*)(wt + (((r9 * 256) + co0 + co_l) * 256 + cin0 + half * 16));
                short8 v0 = src[0];
                short8 v1 = src[1];
                *(short8*)&lds_a[co_l * 40 + half * 16]     = v0;
                *(short8*)&lds_a[co_l * 40 + half * 16 + 8] = v1;
            }
            __syncthreads();
            const int kh = r9 / 3;
            const int kw = r9 % 3;
            short8 af[4], bf[4];
#pragma unroll
            for (int j = 0; j < 4; ++j)
                bf[j] = *(const short8*)&lds_x[((wrow + j + kh) * 18 + (l15 + kw)) * 40 + quad * 8];
#pragma unroll
            for (int i = 0; i < 4; ++i)
                af[i] = *(const short8*)&lds_a[(wco + i * 16 + l15) * 40 + quad * 8];
#pragma unroll
            for (int i = 0; i < 4; ++i)
#pragma unroll
                for (int j = 0; j < 4; ++j)
                    acc[i][j] = __builtin_amdgcn_mfma_f32_16x16x32_bf16(af[i], bf[j], acc[i][j], 0, 0, 0);
            __syncthreads();
        }
    }
    const float a0 = alpha[0];
#pragma unroll
    for (int i = 0; i < 4; ++i) {
        int cob = co0 + wco + i * 16 + quad * 4;
#pragma unroll
        for (int j = 0; j < 4; ++j) {
            int hh = h0 + wrow + j;
            int ww = w0 + l15;
            if (ww < 56) {
#pragma unroll
                for (int r = 0; r < 4; ++r) {
                    int cog = cob + r;
                    out[((b * 256 + cog) * 56 + hh) * 56 + ww] = acc[i][j][r] * a0 + bias[cog];
                }
            }
        }
    }
}

extern "C" void kernel_launch(void* const* d_in, const int* in_sizes, int n_in,
                              void* d_out, int out_size, void* d_ws, size_t ws_size,
                              hipStream_t stream) {
    const float* x      = (const float*)d_in[0];
    const float* weight = (const float*)d_in[1];
    const float* alpha  = (const float*)d_in[2];
    const float* bias   = (const float*)d_in[3];
    float* out = (float*)d_out;

    float*    part = (float*)d_ws;                                  // 1024 B (256 partials)
    uchar_t*  wtf8 = (uchar_t*)((char*)d_ws + 1024);                // 589824 B (i8), region reserves 1179648
    ushort_t* wt16 = (ushort_t*)((char*)d_ws + 1024);               // fallback bf16 layout (same region)
    ushort_t* xp   = (ushort_t*)((char*)d_ws + 1024 + 1179648);     // 55115776 B
    const size_t NEED = 1024 + 1179648 + 55115776;

    absmean_kernel<<<256, 256, 0, stream>>>(weight, part);

    if (ws_size >= NEED) {
        dim3 pgrid(51, 4, 32);
        prep_kernel<<<pgrid, 256, 0, stream>>>(x, weight, part, wtf8, xp);
        dim3 grid(98, 32);
        conv_mfma6_kernel<<<grid, 256, 0, stream>>>(xp, wtf8, alpha, bias, out);
    } else {
        ternarize_kernel<<<N_W / 256, 256, 0, stream>>>(weight, part, wt16);
        dim3 grid(28, 32, 2);
        conv_mfma_fallback_kernel<<<grid, 256, 0, stream>>>(x, wt16, alpha, bias, out);
    }
}